// Round 2
// baseline (5480.374 us; speedup 1.0000x reference)
//
#include <hip/hip_runtime.h>
#include <cstdint>
#include <cstddef>

// Problem constants
#define B_  128
#define T_  512
#define F_  128
#define U_  512
#define G3  1536   // 3*U

// Persistent-kernel partition:
//   8 groups (16 batch rows each) x 32 WGs (16 GRU units each) = 256 WGs, 1/CU.
#define NGRP 8
#define MB   16    // batch rows per group
#define GN   32    // WGs per group (split over U)
#define UC   16    // units per WG
#define WROW 48    // 3*UC weight rows per matrix slice
#define WPAD 520   // 512 + 8 halfs padding (16B) -> 2-way-max LDS bank aliasing

typedef __attribute__((ext_vector_type(8))) _Float16 half8;
typedef __attribute__((ext_vector_type(4))) float    f32x4;

__device__ __forceinline__ float sigmoidf_(float x) {
    return 1.0f / (1.0f + __expf(-x));
}

// ---------------- cast x to f16 + zero-init pub/barrier state ----------------
__global__ void cast_init_kernel(const float* __restrict__ x,
                                 _Float16* __restrict__ xh,
                                 _Float16* __restrict__ h1pub,
                                 _Float16* __restrict__ h2pub,
                                 unsigned int* __restrict__ gbar) {
    size_t i      = (size_t)blockIdx.x * blockDim.x + threadIdx.x;
    size_t stride = (size_t)gridDim.x * blockDim.x;
    for (size_t idx = i; idx < (size_t)B_ * T_ * F_; idx += stride)
        xh[idx] = (_Float16)x[idx];
    for (size_t idx = i; idx < (size_t)2 * B_ * U_; idx += stride) {
        h1pub[idx] = (_Float16)0.f;
        h2pub[idx] = (_Float16)0.f;
    }
    // zero ALL barrier counters (8 groups x 64-uint separation = 512 slots;
    // round up to 1024). Previous round zeroed only [0..255] -> groups 4-7
    // started from 0xAAAAAAAA poison and their barrier was a no-op.
    if (blockIdx.x == 0)
        for (int idx = threadIdx.x; idx < 1024; idx += blockDim.x)
            gbar[idx] = 0u;
}

// ---------------- transpose+cast weights: (K, 1536) f32 -> (1536, K) f16 -----
__global__ void transpose_cast_kernel(const float* __restrict__ in,
                                      _Float16* __restrict__ out, int K) {
    __shared__ float tile[32][33];
    int n0 = blockIdx.x * 32;
    int k0 = blockIdx.y * 32;
    int tx = threadIdx.x, ty = threadIdx.y;   // block (32, 8)
#pragma unroll
    for (int i = 0; i < 4; ++i)
        tile[ty + i * 8][tx] = in[(size_t)(k0 + ty + i * 8) * G3 + (n0 + tx)];
    __syncthreads();
#pragma unroll
    for (int i = 0; i < 4; ++i)
        out[(size_t)(n0 + ty + i * 8) * K + (k0 + tx)] =
            (_Float16)tile[tx][ty + i * 8];
}

// ---------------- GX1 = x @ W1   (M=65536 rows in (t,b)-major, K=128, N=1536)
// A: xh (B,T,F) f16 row-major; B: w1t (1536,128) f16 (n-major). No bias (folded
// into the recurrent combine). Output f16 (T,B,1536).
__global__ __launch_bounds__(256) void gemm_gx1_kernel(
    const _Float16* __restrict__ xh,
    const _Float16* __restrict__ w1t,
    _Float16* __restrict__ gx1) {
    int bx = blockIdx.x;          // 12288 = 1024 m-blocks * 12 n-blocks
    int mb = bx / 12, nb = bx % 12;
    int wave = threadIdx.x >> 6, lane = threadIdx.x & 63;
    int wm = wave >> 1, wn = wave & 1;
    int am = lane & 15, aq = lane >> 4;

    // A fragments: 2 m-tiles x 4 k-chunks, loaded once, reused over n.
    half8 af[2][4];
#pragma unroll
    for (int mt = 0; mt < 2; ++mt) {
        int mo = mb * 64 + wm * 32 + mt * 16 + am;   // output row (t*128+b)
        int b = mo & 127, t = mo >> 7;
        const _Float16* ap = xh + ((size_t)b * T_ + t) * F_ + aq * 8;
#pragma unroll
        for (int kc = 0; kc < 4; ++kc)
            af[mt][kc] = *(const half8*)(ap + kc * 32);
    }

#pragma unroll
    for (int nt = 0; nt < 4; ++nt) {
        int n0 = nb * 128 + wn * 64 + nt * 16;
        f32x4 acc0 = {0.f, 0.f, 0.f, 0.f};
        f32x4 acc1 = {0.f, 0.f, 0.f, 0.f};
#pragma unroll
        for (int kc = 0; kc < 4; ++kc) {
            half8 bf = *(const half8*)(w1t + (size_t)(n0 + am) * F_ + kc * 32 + aq * 8);
            acc0 = __builtin_amdgcn_mfma_f32_16x16x32_f16(af[0][kc], bf, acc0, 0, 0, 0);
            acc1 = __builtin_amdgcn_mfma_f32_16x16x32_f16(af[1][kc], bf, acc1, 0, 0, 0);
        }
        int col = lane & 15, rb = (lane >> 4) * 4;
        int mbase0 = mb * 64 + wm * 32 + 0 * 16;
        int mbase1 = mb * 64 + wm * 32 + 1 * 16;
#pragma unroll
        for (int i = 0; i < 4; ++i) {
            gx1[(size_t)(mbase0 + rb + i) * G3 + n0 + col] = (_Float16)acc0[i];
            gx1[(size_t)(mbase1 + rb + i) * G3 + n0 + col] = (_Float16)acc1[i];
        }
    }
}

// ---------------- fused persistent 2-layer GRU recurrence --------------------
// Round r: layer-1 step r (wave 0),  layer-2 step r-1 (waves 1: gx2, 2: rec2).
// One group-local barrier per round.
__global__ __launch_bounds__(256, 1) void gru_persist_kernel(
    const _Float16* __restrict__ gx1,   // (T,B,1536) f16
    const _Float16* __restrict__ u1t,   // (1536,512) f16  U1^T
    const _Float16* __restrict__ w2t,   // (1536,512) f16  W2^T
    const _Float16* __restrict__ u2t,   // (1536,512) f16  U2^T
    const float* __restrict__ bi1, const float* __restrict__ br1,
    const float* __restrict__ bi2, const float* __restrict__ br2,
    _Float16* __restrict__ h1pub,       // (2,128,512) f16 double-buffered
    _Float16* __restrict__ h2pub,       // (2,128,512) f16
    float* __restrict__ h2fin,          // (128,512) f32
    unsigned int* __restrict__ gbar) {
    // Static LDS: 3*48*520*2 + 9*16*17*4 + 2*256*4 = 161,600 B (<= 163,840)
    __shared__ _Float16 wsl[3 * WROW * WPAD];
    __shared__ float    scratch[9 * 16 * 17];
    __shared__ float    h1own[256];
    __shared__ float    h2own[256];

    const int tid  = threadIdx.x;
    const int bx   = blockIdx.x;
    const int grp  = bx & 7;        // batch group (XCD-affine under RR dispatch)
    const int j    = bx >> 3;       // u-slice 0..31
    const int wave = tid >> 6, lane = tid & 63;
    const int row0 = grp * MB;
    const int u0   = j * UC;

    // ---- stage weight slices into LDS (rows = gate-cols of U1/W2/U2) ----
    for (int idx = tid; idx < 3 * WROW * 64; idx += 256) {
        int m    = idx / (WROW * 64);
        int rem  = idx % (WROW * 64);
        int n    = rem / 64;
        int koff = (rem % 64) * 8;
        const _Float16* src = (m == 0) ? u1t : (m == 1) ? w2t : u2t;
        int gcol = (n / UC) * U_ + u0 + (n % UC);
        half8 v = *(const half8*)(src + (size_t)gcol * U_ + koff);
        *(half8*)(wsl + (size_t)m * WROW * WPAD + (size_t)n * WPAD + koff) = v;
    }

    // ---- per-thread combine role: (cb, cu) over the 16x16 own-slice ----
    const int cb = tid >> 4, cu = tid & 15;
    const int c_z = u0 + cu, c_r = U_ + u0 + cu, c_h = 2 * U_ + u0 + cu;
    const float vbi1z = bi1[c_z], vbi1r = bi1[c_r], vbi1h = bi1[c_h];
    const float vbr1z = br1[c_z], vbr1r = br1[c_r], vbr1h = br1[c_h];
    const float vbi2z = bi2[c_z], vbi2r = bi2[c_r], vbi2h = bi2[c_h];
    const float vbr2z = br2[c_z], vbr2r = br2[c_r], vbr2h = br2[c_h];

    h1own[tid] = 0.f;
    h2own[tid] = 0.f;
    __syncthreads();

    unsigned int* cnt = gbar + (size_t)grp * 64;   // 256B-separated counters

    const int am = lane & 15, aq = lane >> 4;      // A-frag: m, k-quad
    const int bn = lane & 15, bq = lane >> 4;      // B-frag: n, k-quad

    for (int r = 0; r <= T_; ++r) {
        // -- prefetch this round's gx1 (layer-1 combine inputs) --
        _Float16 gz1r = (_Float16)0.f, gr1r = (_Float16)0.f, gh1r = (_Float16)0.f;
        if (r < T_) {
            const _Float16* g = gx1 + ((size_t)r * B_ + row0 + cb) * G3;
            gz1r = g[c_z]; gr1r = g[c_r]; gh1r = g[c_h];
        }

        // -- matmul phase --
        // wave0: rec1 = h1_{r-1} @ U1slice   (r < T)
        // wave1: gx2p = h1_{r-1} @ W2slice   (r >= 1)
        // wave2: rec2 = h2_{r-2} @ U2slice   (r >= 1)
        bool active = (wave == 0 && r < T_) || ((wave == 1 || wave == 2) && r >= 1);
        f32x4 acc0 = {0.f, 0.f, 0.f, 0.f};
        f32x4 acc1 = {0.f, 0.f, 0.f, 0.f};
        f32x4 acc2 = {0.f, 0.f, 0.f, 0.f};
        if (active) {
            const _Float16* hsrc = (wave == 2)
                ? (h2pub + (size_t)(r & 1) * B_ * U_)
                : (h1pub + (size_t)((r + 1) & 1) * B_ * U_);
            const _Float16* wbase = wsl + (size_t)wave * WROW * WPAD;
            const _Float16* aptr  = hsrc + (size_t)(row0 + am) * U_ + aq * 8;
#pragma unroll
            for (int kc = 0; kc < 16; ++kc) {
                half8 afr = *(const half8*)(aptr + kc * 32);
                half8 bf0 = *(const half8*)(wbase + (size_t)(0 * UC + bn) * WPAD + kc * 32 + bq * 8);
                half8 bf1 = *(const half8*)(wbase + (size_t)(1 * UC + bn) * WPAD + kc * 32 + bq * 8);
                half8 bf2 = *(const half8*)(wbase + (size_t)(2 * UC + bn) * WPAD + kc * 32 + bq * 8);
                acc0 = __builtin_amdgcn_mfma_f32_16x16x32_f16(afr, bf0, acc0, 0, 0, 0);
                acc1 = __builtin_amdgcn_mfma_f32_16x16x32_f16(afr, bf1, acc1, 0, 0, 0);
                acc2 = __builtin_amdgcn_mfma_f32_16x16x32_f16(afr, bf2, acc2, 0, 0, 0);
            }
            // write to scratch tiles [wave*3 + gate][16][17]
            int col = lane & 15, rb4 = (lane >> 4) * 4;
            float* sp = scratch + (size_t)(wave * 3) * 272;
#pragma unroll
            for (int i = 0; i < 4; ++i) {
                sp[0 * 272 + (rb4 + i) * 17 + col] = acc0[i];
                sp[1 * 272 + (rb4 + i) * 17 + col] = acc1[i];
                sp[2 * 272 + (rb4 + i) * 17 + col] = acc2[i];
            }
        }
        __syncthreads();

        // -- combine layer 1: h1_r --
        if (r < T_) {
            float rz = scratch[0 * 272 + cb * 17 + cu];
            float rr = scratch[1 * 272 + cb * 17 + cu];
            float rh = scratch[2 * 272 + cb * 17 + cu];
            float z  = sigmoidf_((float)gz1r + vbi1z + rz + vbr1z);
            float rg = sigmoidf_((float)gr1r + vbi1r + rr + vbr1r);
            float hh = fmaxf(0.f, (float)gh1r + vbi1h + rg * (rh + vbr1h));
            float hold = h1own[tid];
            float hnew = z * hold + (1.f - z) * hh;
            h1own[tid] = hnew;
            h1pub[(size_t)(r & 1) * B_ * U_ + (size_t)(row0 + cb) * U_ + u0 + cu] =
                (_Float16)hnew;
        }

        // -- combine layer 2: h2_{r-1} --
        if (r >= 1) {
            int s = r - 1;
            float gz = scratch[3 * 272 + cb * 17 + cu] + vbi2z;
            float gr = scratch[4 * 272 + cb * 17 + cu] + vbi2r;
            float gh = scratch[5 * 272 + cb * 17 + cu] + vbi2h;
            float rz = scratch[6 * 272 + cb * 17 + cu] + vbr2z;
            float rr = scratch[7 * 272 + cb * 17 + cu] + vbr2r;
            float rh = scratch[8 * 272 + cb * 17 + cu] + vbr2h;
            float z  = sigmoidf_(gz + rz);
            float rg = sigmoidf_(gr + rr);
            float hh = fmaxf(0.f, gh + rg * rh);
            float hold = h2own[tid];
            float hnew = z * hold + (1.f - z) * hh;
            h2own[tid] = hnew;
            h2pub[(size_t)(s & 1) * B_ * U_ + (size_t)(row0 + cb) * U_ + u0 + cu] =
                (_Float16)hnew;
            if (s == T_ - 1)
                h2fin[(size_t)(row0 + cb) * U_ + u0 + cu] = hnew;
        }

        // -- group barrier (32 WGs), agent scope for cross-XCD correctness --
        __syncthreads();
        if (tid == 0) {
            __hip_atomic_fetch_add(cnt, 1u, __ATOMIC_RELEASE, __HIP_MEMORY_SCOPE_AGENT);
            unsigned int target = (unsigned int)(r + 1) * GN;
            while (__hip_atomic_load(cnt, __ATOMIC_ACQUIRE, __HIP_MEMORY_SCOPE_AGENT) < target) {}
        }
        __syncthreads();
    }
}

// ---------------- head: out = h2_final @ Wd + bd -----------------------------
__global__ void head_kernel(const float* __restrict__ h2fin,
                            const float* __restrict__ Wd,
                            const float* __restrict__ bd,
                            float* __restrict__ out) {
    int b = blockIdx.x;
    int lane = threadIdx.x;   // 64
    float s = 0.f;
#pragma unroll
    for (int u = lane; u < U_; u += 64)
        s += h2fin[(size_t)b * U_ + u] * Wd[u];
#pragma unroll
    for (int off = 32; off > 0; off >>= 1)
        s += __shfl_down(s, off, 64);
    if (lane == 0) out[b] = s + bd[0];
}

// ---------------- launch -----------------------------------------------------
extern "C" void kernel_launch(void* const* d_in, const int* in_sizes, int n_in,
                              void* d_out, int out_size, void* d_ws, size_t ws_size,
                              hipStream_t stream) {
    (void)in_sizes; (void)n_in; (void)out_size; (void)ws_size;

    const float* x   = (const float*)d_in[0];
    const float* W1  = (const float*)d_in[1];
    const float* U1  = (const float*)d_in[2];
    const float* bi1 = (const float*)d_in[3];
    const float* br1 = (const float*)d_in[4];
    const float* W2  = (const float*)d_in[5];
    const float* U2  = (const float*)d_in[6];
    const float* bi2 = (const float*)d_in[7];
    const float* br2 = (const float*)d_in[8];
    const float* Wd  = (const float*)d_in[9];
    const float* bd  = (const float*)d_in[10];

    char* w = (char*)d_ws;
    // workspace layout (bytes), everything 256-aligned
    constexpr size_t OFF_XH   = 0;                          // 16,777,216
    constexpr size_t OFF_W1T  = OFF_XH  + (size_t)B_ * T_ * F_ * 2;       // +16777216
    constexpr size_t OFF_U1T  = OFF_W1T + (size_t)G3 * F_ * 2;            // +393216
    constexpr size_t OFF_W2T  = OFF_U1T + (size_t)G3 * U_ * 2;            // +1572864
    constexpr size_t OFF_U2T  = OFF_W2T + (size_t)G3 * U_ * 2;
    constexpr size_t OFF_GX1  = OFF_U2T + (size_t)G3 * U_ * 2;
    constexpr size_t OFF_H1P  = OFF_GX1 + (size_t)T_ * B_ * G3 * 2;       // +201326592
    constexpr size_t OFF_H2P  = OFF_H1P + (size_t)2 * B_ * U_ * 2;
    constexpr size_t OFF_H2F  = OFF_H2P + (size_t)2 * B_ * U_ * 2;
    constexpr size_t OFF_BAR  = OFF_H2F + (size_t)B_ * U_ * 4;

    _Float16* xh   = (_Float16*)(w + OFF_XH);
    _Float16* w1t  = (_Float16*)(w + OFF_W1T);
    _Float16* u1t  = (_Float16*)(w + OFF_U1T);
    _Float16* w2t  = (_Float16*)(w + OFF_W2T);
    _Float16* u2t  = (_Float16*)(w + OFF_U2T);
    _Float16* gx1  = (_Float16*)(w + OFF_GX1);
    _Float16* h1p  = (_Float16*)(w + OFF_H1P);
    _Float16* h2p  = (_Float16*)(w + OFF_H2P);
    float*    h2f  = (float*)   (w + OFF_H2F);
    unsigned int* gbar = (unsigned int*)(w + OFF_BAR);

    cast_init_kernel<<<1024, 256, 0, stream>>>(x, xh, h1p, h2p, gbar);

    dim3 tb(32, 8);
    transpose_cast_kernel<<<dim3(48, 4),  tb, 0, stream>>>(W1, w1t, F_);
    transpose_cast_kernel<<<dim3(48, 16), tb, 0, stream>>>(U1, u1t, U_);
    transpose_cast_kernel<<<dim3(48, 16), tb, 0, stream>>>(W2, w2t, U_);
    transpose_cast_kernel<<<dim3(48, 16), tb, 0, stream>>>(U2, u2t, U_);

    gemm_gx1_kernel<<<12288, 256, 0, stream>>>(xh, w1t, gx1);

    gru_persist_kernel<<<256, 256, 0, stream>>>(gx1, u1t, w2t, u2t,
                                                bi1, br1, bi2, br2,
                                                h1p, h2p, h2f, gbar);

    head_kernel<<<128, 64, 0, stream>>>(h2f, Wd, bd, (float*)d_out);
}

// Round 4
// 2021.063 us; speedup vs baseline: 2.7116x; 2.7116x over previous
//
#include <hip/hip_runtime.h>
#include <cstdint>
#include <cstddef>

// Problem constants
#define B_  128
#define T_  512
#define F_  128
#define U_  512
#define G3  1536   // 3*U

// Persistent-kernel partition:
//   8 groups (16 batch rows each) x 32 WGs (16 GRU units each) = 256 WGs, 1/CU.
#define NGRP 8
#define MB   16    // batch rows per group
#define GN   32    // WGs per group (split over U)
#define UC   16    // units per WG

typedef __attribute__((ext_vector_type(8))) _Float16 half8;
typedef __attribute__((ext_vector_type(4))) float    f32x4;

union U16x2 { unsigned int u; _Float16 h[2]; };

__device__ __forceinline__ float sigmoidf_(float x) {
    return 1.0f / (1.0f + __expf(-x));
}

// 16 x dwordx4 LLC-coherent loads (64-bit VGPR address form), no wait.
// Covers one 16-row x K=512 f16 panel slice for this lane.
__device__ __forceinline__ void load_h_row_issue(const _Float16* aptr,
                                                 half8* f) {
    asm volatile(
        "global_load_dwordx4 %0, %16, off offset:0 sc0 sc1\n\t"
        "global_load_dwordx4 %1, %16, off offset:64 sc0 sc1\n\t"
        "global_load_dwordx4 %2, %16, off offset:128 sc0 sc1\n\t"
        "global_load_dwordx4 %3, %16, off offset:192 sc0 sc1\n\t"
        "global_load_dwordx4 %4, %16, off offset:256 sc0 sc1\n\t"
        "global_load_dwordx4 %5, %16, off offset:320 sc0 sc1\n\t"
        "global_load_dwordx4 %6, %16, off offset:384 sc0 sc1\n\t"
        "global_load_dwordx4 %7, %16, off offset:448 sc0 sc1\n\t"
        "global_load_dwordx4 %8, %16, off offset:512 sc0 sc1\n\t"
        "global_load_dwordx4 %9, %16, off offset:576 sc0 sc1\n\t"
        "global_load_dwordx4 %10, %16, off offset:640 sc0 sc1\n\t"
        "global_load_dwordx4 %11, %16, off offset:704 sc0 sc1\n\t"
        "global_load_dwordx4 %12, %16, off offset:768 sc0 sc1\n\t"
        "global_load_dwordx4 %13, %16, off offset:832 sc0 sc1\n\t"
        "global_load_dwordx4 %14, %16, off offset:896 sc0 sc1\n\t"
        "global_load_dwordx4 %15, %16, off offset:960 sc0 sc1"
        : "=&v"(f[0]), "=&v"(f[1]), "=&v"(f[2]), "=&v"(f[3]),
          "=&v"(f[4]), "=&v"(f[5]), "=&v"(f[6]), "=&v"(f[7]),
          "=&v"(f[8]), "=&v"(f[9]), "=&v"(f[10]), "=&v"(f[11]),
          "=&v"(f[12]), "=&v"(f[13]), "=&v"(f[14]), "=&v"(f[15])
        : "v"((uint64_t)(uintptr_t)aptr)
        : "memory");
}

// vmcnt drain tied to the fragment registers so MFMAs can't be hoisted above it.
__device__ __forceinline__ void load_h_row_wait(half8* f) {
    asm volatile(
        "s_waitcnt vmcnt(0)"
        : "+v"(f[0]), "+v"(f[1]), "+v"(f[2]), "+v"(f[3]),
          "+v"(f[4]), "+v"(f[5]), "+v"(f[6]), "+v"(f[7]),
          "+v"(f[8]), "+v"(f[9]), "+v"(f[10]), "+v"(f[11]),
          "+v"(f[12]), "+v"(f[13]), "+v"(f[14]), "+v"(f[15])
        :
        : "memory");
}

// ---------------- cast x to f16 + zero-init pub/barrier state ----------------
__global__ void cast_init_kernel(const float* __restrict__ x,
                                 _Float16* __restrict__ xh,
                                 _Float16* __restrict__ h1pub,
                                 _Float16* __restrict__ h2pub,
                                 unsigned int* __restrict__ gbar) {
    size_t i      = (size_t)blockIdx.x * blockDim.x + threadIdx.x;
    size_t stride = (size_t)gridDim.x * blockDim.x;
    for (size_t idx = i; idx < (size_t)B_ * T_ * F_; idx += stride)
        xh[idx] = (_Float16)x[idx];
    for (size_t idx = i; idx < (size_t)2 * B_ * U_; idx += stride) {
        h1pub[idx] = (_Float16)0.f;
        h2pub[idx] = (_Float16)0.f;
    }
    if (blockIdx.x == 0)
        for (int idx = threadIdx.x; idx < 1024; idx += blockDim.x)
            gbar[idx] = 0u;
}

// ---------------- transpose+cast weights: (K, 1536) f32 -> (1536, K) f16 -----
__global__ void transpose_cast_kernel(const float* __restrict__ in,
                                      _Float16* __restrict__ out, int K) {
    __shared__ float tile[32][33];
    int n0 = blockIdx.x * 32;
    int k0 = blockIdx.y * 32;
    int tx = threadIdx.x, ty = threadIdx.y;   // block (32, 8)
#pragma unroll
    for (int i = 0; i < 4; ++i)
        tile[ty + i * 8][tx] = in[(size_t)(k0 + ty + i * 8) * G3 + (n0 + tx)];
    __syncthreads();
#pragma unroll
    for (int i = 0; i < 4; ++i)
        out[(size_t)(n0 + ty + i * 8) * K + (k0 + tx)] =
            (_Float16)tile[tx][ty + i * 8];
}

// ---------------- GX1 = x @ W1 ----------------------------------------------
__global__ __launch_bounds__(256) void gemm_gx1_kernel(
    const _Float16* __restrict__ xh,
    const _Float16* __restrict__ w1t,
    _Float16* __restrict__ gx1) {
    int bx = blockIdx.x;          // 12288 = 1024 m-blocks * 12 n-blocks
    int mb = bx / 12, nb = bx % 12;
    int wave = threadIdx.x >> 6, lane = threadIdx.x & 63;
    int wm = wave >> 1, wn = wave & 1;
    int am = lane & 15, aq = lane >> 4;

    half8 af[2][4];
#pragma unroll
    for (int mt = 0; mt < 2; ++mt) {
        int mo = mb * 64 + wm * 32 + mt * 16 + am;   // output row (t*128+b)
        int b = mo & 127, t = mo >> 7;
        const _Float16* ap = xh + ((size_t)b * T_ + t) * F_ + aq * 8;
#pragma unroll
        for (int kc = 0; kc < 4; ++kc)
            af[mt][kc] = *(const half8*)(ap + kc * 32);
    }

#pragma unroll
    for (int nt = 0; nt < 4; ++nt) {
        int n0 = nb * 128 + wn * 64 + nt * 16;
        f32x4 acc0 = {0.f, 0.f, 0.f, 0.f};
        f32x4 acc1 = {0.f, 0.f, 0.f, 0.f};
#pragma unroll
        for (int kc = 0; kc < 4; ++kc) {
            half8 bf = *(const half8*)(w1t + (size_t)(n0 + am) * F_ + kc * 32 + aq * 8);
            acc0 = __builtin_amdgcn_mfma_f32_16x16x32_f16(af[0][kc], bf, acc0, 0, 0, 0);
            acc1 = __builtin_amdgcn_mfma_f32_16x16x32_f16(af[1][kc], bf, acc1, 0, 0, 0);
        }
        int col = lane & 15, rb = (lane >> 4) * 4;
        int mbase0 = mb * 64 + wm * 32 + 0 * 16;
        int mbase1 = mb * 64 + wm * 32 + 1 * 16;
#pragma unroll
        for (int i = 0; i < 4; ++i) {
            gx1[(size_t)(mbase0 + rb + i) * G3 + n0 + col] = (_Float16)acc0[i];
            gx1[(size_t)(mbase1 + rb + i) * G3 + n0 + col] = (_Float16)acc1[i];
        }
    }
}

// ---------------- fused persistent 2-layer GRU recurrence --------------------
// Weights live in REGISTERS (48 half8/wave, loop-invariant). Cross-WG h moves
// via LLC-coherent (sc0 sc1) accesses; barrier is relaxed atomics only ->
// no buffer_inv / buffer_wbl2 anywhere in the loop.
__global__ __launch_bounds__(256, 1) void gru_persist_kernel(
    const _Float16* __restrict__ gx1,   // (T,B,1536) f16
    const _Float16* __restrict__ u1t,   // (1536,512) f16  U1^T
    const _Float16* __restrict__ w2t,   // (1536,512) f16  W2^T
    const _Float16* __restrict__ u2t,   // (1536,512) f16  U2^T
    const float* __restrict__ bi1, const float* __restrict__ br1,
    const float* __restrict__ bi2, const float* __restrict__ br2,
    _Float16* __restrict__ h1pub,       // (2,128,512) f16 double-buffered
    _Float16* __restrict__ h2pub,       // (2,128,512) f16
    float* __restrict__ h2fin,          // (128,512) f32
    unsigned int* __restrict__ gbar) {
    __shared__ float scratch[9 * 16 * 17];   // 9 tiles x 16 x (16+1)

    const int tid  = threadIdx.x;
    const int bx   = blockIdx.x;
    const int grp  = bx & 7;        // batch group
    const int j    = bx >> 3;       // u-slice 0..31
    const int wave = tid >> 6, lane = tid & 63;
    const int row0 = grp * MB;
    const int u0   = j * UC;

    const int am = lane & 15, aq = lane >> 4;      // A-frag: m row, k-quad
    const int bn = lane & 15, bq = lane >> 4;      // B-frag: n col, k-quad

    // ---- preload this wave's 48 B-fragments into registers (loop-invariant) --
    // wave0: U1 slice, wave1: W2 slice, wave2: U2 slice; wave3 idle in matmul.
    half8 bfr[3][16];
    if (wave < 3) {
        const _Float16* wsrc = (wave == 0) ? u1t : (wave == 1) ? w2t : u2t;
#pragma unroll
        for (int g = 0; g < 3; ++g)
#pragma unroll
            for (int kc = 0; kc < 16; ++kc)
                bfr[g][kc] = *(const half8*)(
                    wsrc + (size_t)(g * U_ + u0 + bn) * U_ + kc * 32 + bq * 8);
    }

    // ---- combine roles: threads 0..127 layer1, 128..255 layer2; 2 units each
    const int layer = tid >> 7;
    const int lt    = tid & 127;
    const int cb2   = lt >> 3;           // batch row 0..15
    const int up    = lt & 7;            // unit pair -> units u0+2up, u0+2up+1
    const int cuA   = 2 * up;
    const int cA    = u0 + cuA;

    const float* bi = (layer == 0) ? bi1 : bi2;
    const float* br = (layer == 0) ? br1 : br2;
    const float biz0 = bi[cA],            biz1 = bi[cA + 1];
    const float bir0 = bi[U_ + cA],       bir1 = bi[U_ + cA + 1];
    const float bih0 = bi[2 * U_ + cA],   bih1 = bi[2 * U_ + cA + 1];
    const float brz0 = br[cA],            brz1 = br[cA + 1];
    const float brr0 = br[U_ + cA],       brr1 = br[U_ + cA + 1];
    const float brh0 = br[2 * U_ + cA],   brh1 = br[2 * U_ + cA + 1];

    float s0 = 0.f, s1 = 0.f;            // own h-state (registers)

    unsigned int* cnt = gbar + (size_t)grp * 64;   // 256B-separated counters
    const size_t a_elem = (size_t)(row0 + am) * U_ + aq * 8;

    for (int r = 0; r <= T_; ++r) {
        // -- prefetch this round's gx1 (layer-1 combine inputs, packed u32) --
        unsigned int gzu = 0, gru = 0, ghu = 0;
        if (layer == 0 && r < T_) {
            const unsigned int* g = (const unsigned int*)(
                gx1 + ((size_t)r * B_ + row0 + cb2) * G3);
            gzu = g[(u0 >> 1) + up];
            gru = g[((U_ + u0) >> 1) + up];
            ghu = g[((2 * U_ + u0) >> 1) + up];
        }

        // -- matmul phase --
        // wave0: rec1 = h1_{r-1} @ U1slice   (r < T)
        // wave1: gx2p = h1_{r-1} @ W2slice   (r >= 1)
        // wave2: rec2 = h2_{r-2} @ U2slice   (r >= 1)
        bool active = (wave == 0 && r < T_) || ((wave == 1 || wave == 2) && r >= 1);
        if (active) {
            const _Float16* hsrc = (wave == 2)
                ? (h2pub + (size_t)(r & 1) * B_ * U_)
                : (h1pub + (size_t)((r + 1) & 1) * B_ * U_);
            half8 f[16];
            load_h_row_issue(hsrc + a_elem, f);    // LLC-coherent, pipelined
            load_h_row_wait(f);                    // single vmcnt drain

            f32x4 acc0 = {0.f, 0.f, 0.f, 0.f};
            f32x4 acc1 = {0.f, 0.f, 0.f, 0.f};
            f32x4 acc2 = {0.f, 0.f, 0.f, 0.f};
#pragma unroll
            for (int kc = 0; kc < 16; ++kc) {
                acc0 = __builtin_amdgcn_mfma_f32_16x16x32_f16(f[kc], bfr[0][kc], acc0, 0, 0, 0);
                acc1 = __builtin_amdgcn_mfma_f32_16x16x32_f16(f[kc], bfr[1][kc], acc1, 0, 0, 0);
                acc2 = __builtin_amdgcn_mfma_f32_16x16x32_f16(f[kc], bfr[2][kc], acc2, 0, 0, 0);
            }
            int col = lane & 15, rb4 = (lane >> 4) * 4;
            float* sp = scratch + (size_t)(wave * 3) * 272;
#pragma unroll
            for (int i = 0; i < 4; ++i) {
                sp[0 * 272 + (rb4 + i) * 17 + col] = acc0[i];
                sp[1 * 272 + (rb4 + i) * 17 + col] = acc1[i];
                sp[2 * 272 + (rb4 + i) * 17 + col] = acc2[i];
            }
        }
        __syncthreads();

        // -- combine (layer1 on threads 0..127, layer2 on 128..255, parallel) --
        if (layer == 0) {
            if (r < T_) {
                float rz0v = scratch[0 * 272 + cb2 * 17 + cuA];
                float rz1v = scratch[0 * 272 + cb2 * 17 + cuA + 1];
                float rr0v = scratch[1 * 272 + cb2 * 17 + cuA];
                float rr1v = scratch[1 * 272 + cb2 * 17 + cuA + 1];
                float rh0v = scratch[2 * 272 + cb2 * 17 + cuA];
                float rh1v = scratch[2 * 272 + cb2 * 17 + cuA + 1];
                U16x2 gz, gr, gh; gz.u = gzu; gr.u = gru; gh.u = ghu;
                float z0 = sigmoidf_((float)gz.h[0] + biz0 + rz0v + brz0);
                float z1 = sigmoidf_((float)gz.h[1] + biz1 + rz1v + brz1);
                float rg0 = sigmoidf_((float)gr.h[0] + bir0 + rr0v + brr0);
                float rg1 = sigmoidf_((float)gr.h[1] + bir1 + rr1v + brr1);
                float hh0 = fmaxf(0.f, (float)gh.h[0] + bih0 + rg0 * (rh0v + brh0));
                float hh1 = fmaxf(0.f, (float)gh.h[1] + bih1 + rg1 * (rh1v + brh1));
                s0 = z0 * s0 + (1.f - z0) * hh0;
                s1 = z1 * s1 + (1.f - z1) * hh1;
                U16x2 p; p.h[0] = (_Float16)s0; p.h[1] = (_Float16)s1;
                unsigned int* dst = (unsigned int*)(
                    h1pub + (size_t)(r & 1) * B_ * U_ + (size_t)(row0 + cb2) * U_ + u0) + up;
                __hip_atomic_store(dst, p.u, __ATOMIC_RELAXED, __HIP_MEMORY_SCOPE_AGENT);
            }
        } else {
            if (r >= 1) {
                int s = r - 1;
                float gz0 = scratch[3 * 272 + cb2 * 17 + cuA]     + biz0;
                float gz1 = scratch[3 * 272 + cb2 * 17 + cuA + 1] + biz1;
                float gr0 = scratch[4 * 272 + cb2 * 17 + cuA]     + bir0;
                float gr1 = scratch[4 * 272 + cb2 * 17 + cuA + 1] + bir1;
                float gh0 = scratch[5 * 272 + cb2 * 17 + cuA]     + bih0;
                float gh1 = scratch[5 * 272 + cb2 * 17 + cuA + 1] + bih1;
                float rz0v = scratch[6 * 272 + cb2 * 17 + cuA]     + brz0;
                float rz1v = scratch[6 * 272 + cb2 * 17 + cuA + 1] + brz1;
                float rr0v = scratch[7 * 272 + cb2 * 17 + cuA]     + brr0;
                float rr1v = scratch[7 * 272 + cb2 * 17 + cuA + 1] + brr1;
                float rh0v = scratch[8 * 272 + cb2 * 17 + cuA]     + brh0;
                float rh1v = scratch[8 * 272 + cb2 * 17 + cuA + 1] + brh1;
                float z0 = sigmoidf_(gz0 + rz0v);
                float z1 = sigmoidf_(gz1 + rz1v);
                float rg0 = sigmoidf_(gr0 + rr0v);
                float rg1 = sigmoidf_(gr1 + rr1v);
                float hh0 = fmaxf(0.f, gh0 + rg0 * rh0v);
                float hh1 = fmaxf(0.f, gh1 + rg1 * rh1v);
                s0 = z0 * s0 + (1.f - z0) * hh0;
                s1 = z1 * s1 + (1.f - z1) * hh1;
                U16x2 p; p.h[0] = (_Float16)s0; p.h[1] = (_Float16)s1;
                unsigned int* dst = (unsigned int*)(
                    h2pub + (size_t)(s & 1) * B_ * U_ + (size_t)(row0 + cb2) * U_ + u0) + up;
                __hip_atomic_store(dst, p.u, __ATOMIC_RELAXED, __HIP_MEMORY_SCOPE_AGENT);
                if (s == T_ - 1) {
                    h2fin[(size_t)(row0 + cb2) * U_ + cA]     = s0;
                    h2fin[(size_t)(row0 + cb2) * U_ + cA + 1] = s1;
                }
            }
        }

        // -- group barrier (32 WGs), relaxed atomics at LLC; ordering carried
        //    by __syncthreads' vmcnt drain + LLC point-of-coherence --
        __syncthreads();
        if (tid == 0) {
            __hip_atomic_fetch_add(cnt, 1u, __ATOMIC_RELAXED, __HIP_MEMORY_SCOPE_AGENT);
            unsigned int target = (unsigned int)(r + 1) * GN;
            while (__hip_atomic_load(cnt, __ATOMIC_RELAXED, __HIP_MEMORY_SCOPE_AGENT) < target) {}
        }
        __syncthreads();
    }
}

// ---------------- head: out = h2_final @ Wd + bd -----------------------------
__global__ void head_kernel(const float* __restrict__ h2fin,
                            const float* __restrict__ Wd,
                            const float* __restrict__ bd,
                            float* __restrict__ out) {
    int b = blockIdx.x;
    int lane = threadIdx.x;   // 64
    float s = 0.f;
#pragma unroll
    for (int u = lane; u < U_; u += 64)
        s += h2fin[(size_t)b * U_ + u] * Wd[u];
#pragma unroll
    for (int off = 32; off > 0; off >>= 1)
        s += __shfl_down(s, off, 64);
    if (lane == 0) out[b] = s + bd[0];
}

// ---------------- launch -----------------------------------------------------
extern "C" void kernel_launch(void* const* d_in, const int* in_sizes, int n_in,
                              void* d_out, int out_size, void* d_ws, size_t ws_size,
                              hipStream_t stream) {
    (void)in_sizes; (void)n_in; (void)out_size; (void)ws_size;

    const float* x   = (const float*)d_in[0];
    const float* W1  = (const float*)d_in[1];
    const float* U1  = (const float*)d_in[2];
    const float* bi1 = (const float*)d_in[3];
    const float* br1 = (const float*)d_in[4];
    const float* W2  = (const float*)d_in[5];
    const float* U2  = (const float*)d_in[6];
    const float* bi2 = (const float*)d_in[7];
    const float* br2 = (const float*)d_in[8];
    const float* Wd  = (const float*)d_in[9];
    const float* bd  = (const float*)d_in[10];

    char* w = (char*)d_ws;
    constexpr size_t OFF_XH   = 0;
    constexpr size_t OFF_W1T  = OFF_XH  + (size_t)B_ * T_ * F_ * 2;
    constexpr size_t OFF_U1T  = OFF_W1T + (size_t)G3 * F_ * 2;
    constexpr size_t OFF_W2T  = OFF_U1T + (size_t)G3 * U_ * 2;
    constexpr size_t OFF_U2T  = OFF_W2T + (size_t)G3 * U_ * 2;
    constexpr size_t OFF_GX1  = OFF_U2T + (size_t)G3 * U_ * 2;
    constexpr size_t OFF_H1P  = OFF_GX1 + (size_t)T_ * B_ * G3 * 2;
    constexpr size_t OFF_H2P  = OFF_H1P + (size_t)2 * B_ * U_ * 2;
    constexpr size_t OFF_H2F  = OFF_H2P + (size_t)2 * B_ * U_ * 2;
    constexpr size_t OFF_BAR  = OFF_H2F + (size_t)B_ * U_ * 4;

    _Float16* xh   = (_Float16*)(w + OFF_XH);
    _Float16* w1t  = (_Float16*)(w + OFF_W1T);
    _Float16* u1t  = (_Float16*)(w + OFF_U1T);
    _Float16* w2t  = (_Float16*)(w + OFF_W2T);
    _Float16* u2t  = (_Float16*)(w + OFF_U2T);
    _Float16* gx1  = (_Float16*)(w + OFF_GX1);
    _Float16* h1p  = (_Float16*)(w + OFF_H1P);
    _Float16* h2p  = (_Float16*)(w + OFF_H2P);
    float*    h2f  = (float*)   (w + OFF_H2F);
    unsigned int* gbar = (unsigned int*)(w + OFF_BAR);

    cast_init_kernel<<<1024, 256, 0, stream>>>(x, xh, h1p, h2p, gbar);

    dim3 tb(32, 8);
    transpose_cast_kernel<<<dim3(48, 4),  tb, 0, stream>>>(W1, w1t, F_);
    transpose_cast_kernel<<<dim3(48, 16), tb, 0, stream>>>(U1, u1t, U_);
    transpose_cast_kernel<<<dim3(48, 16), tb, 0, stream>>>(W2, w2t, U_);
    transpose_cast_kernel<<<dim3(48, 16), tb, 0, stream>>>(U2, u2t, U_);

    gemm_gx1_kernel<<<12288, 256, 0, stream>>>(xh, w1t, gx1);

    gru_persist_kernel<<<256, 256, 0, stream>>>(gx1, u1t, w2t, u2t,
                                                bi1, br1, bi2, br2,
                                                h1p, h2p, h2f, gbar);

    head_kernel<<<128, 64, 0, stream>>>(h2f, Wd, bd, (float*)d_out);
}